// Round 3
// baseline (261.171 us; speedup 1.0000x reference)
//
#include <hip/hip_runtime.h>
#include <stdint.h>

typedef short bf16x8 __attribute__((ext_vector_type(8)));
typedef float f32x4 __attribute__((ext_vector_type(4)));
typedef float f32x16 __attribute__((ext_vector_type(16)));

#define MFMA16(a, b, c) __builtin_amdgcn_mfma_f32_16x16x32_bf16((a), (b), (c), 0, 0, 0)
#define MFMA32(a, b, c) __builtin_amdgcn_mfma_f32_32x32x16_bf16((a), (b), (c), 0, 0, 0)

__device__ __forceinline__ unsigned short f2bf(float x) {
  union { float f; unsigned int u; } v; v.f = x;
  unsigned int r = (v.u + 0x7FFFu + ((v.u >> 16) & 1u)) >> 16;
  return (unsigned short)r;
}

__device__ __forceinline__ unsigned int cvtpk(float lo, float hi) {
  unsigned int r;
  asm("v_cvt_pk_bf16_f32 %0, %1, %2" : "=v"(r) : "v"(lo), "v"(hi));
  return r;
}

__device__ __forceinline__ void plswap(unsigned int& a, unsigned int& b) {
  asm("v_permlane32_swap_b32 %0, %1" : "+v"(a), "+v"(b));
}

// ---------------------------------------------------------------- convert
__global__ void __launch_bounds__(256) cvt_f32_bf16(const float* __restrict__ in,
                                                    unsigned short* __restrict__ out,
                                                    int n4) {
  int i = blockIdx.x * blockDim.x + threadIdx.x;
  int stride = gridDim.x * blockDim.x;
  for (; i < n4; i += stride) {
    float4 v = ((const float4*)in)[i];
    ushort4 o;
    o.x = f2bf(v.x); o.y = f2bf(v.y); o.z = f2bf(v.z); o.w = f2bf(v.w);
    ((ushort4*)out)[i] = o;
  }
}

// ---------------------------------------------------------------- GEMM (unchanged from R2)
template <int MODE>
__global__ void __launch_bounds__(256) gemm_bt(const unsigned short* __restrict__ A,
                                               const unsigned short* __restrict__ Bw,
                                               const float* __restrict__ bias,
                                               void* __restrict__ out) {
  constexpr int K = 1024;
  __shared__ unsigned short As[128 * 32];
  __shared__ unsigned short Bs[128 * 32];

  const int tid = threadIdx.x;
  const int wid = tid >> 6;
  const int l = tid & 63;
  const int g = l >> 4;
  const int ln = l & 15;

  const int m0 = blockIdx.y * 128;
  const int n0 = blockIdx.x * 128;
  const int wm = (wid >> 1) * 64;
  const int wn = (wid & 1) * 64;

  f32x4 acc[4][4];
  for (int i = 0; i < 4; ++i)
    for (int j = 0; j < 4; ++j) acc[i][j] = (f32x4){0.f, 0.f, 0.f, 0.f};

  const int s0 = wid * 2;
  const int rowBase = s0 * 16 + (l >> 2);
  const int cb = (l & 3) * 8;

  for (int kt = 0; kt < K; kt += 32) {
    __syncthreads();
#pragma unroll
    for (int i = 0; i < 2; ++i) {
      int row = rowBase + i * 16;
      const unsigned short* ga = A + (size_t)(m0 + row) * K + kt + cb;
      const unsigned short* gb = Bw + (size_t)(n0 + row) * K + kt + cb;
      __builtin_amdgcn_global_load_lds((const __attribute__((address_space(1))) void*)ga,
                                       (__attribute__((address_space(3))) void*)&As[(s0 + i) * 512],
                                       16, 0, 0);
      __builtin_amdgcn_global_load_lds((const __attribute__((address_space(1))) void*)gb,
                                       (__attribute__((address_space(3))) void*)&Bs[(s0 + i) * 512],
                                       16, 0, 0);
    }
    __syncthreads();

    bf16x8 af[4], bfr[4];
#pragma unroll
    for (int mi = 0; mi < 4; ++mi) af[mi] = *(const bf16x8*)&As[(wm + mi * 16 + ln) * 32 + g * 8];
#pragma unroll
    for (int ni = 0; ni < 4; ++ni) bfr[ni] = *(const bf16x8*)&Bs[(wn + ni * 16 + ln) * 32 + g * 8];
#pragma unroll
    for (int mi = 0; mi < 4; ++mi)
#pragma unroll
      for (int ni = 0; ni < 4; ++ni) acc[mi][ni] = MFMA16(af[mi], bfr[ni], acc[mi][ni]);
  }

  const int mBase = m0 + wm + g * 4;
  const int nBase = n0 + wn + ln;

  if (MODE == 3) {
    float* O = (float*)out;
#pragma unroll
    for (int mi = 0; mi < 4; ++mi) {
      int m = mBase + mi * 16;
#pragma unroll
      for (int ni = 0; ni < 4; ++ni) {
        int n = nBase + ni * 16;
        float bv = bias[n];
#pragma unroll
        for (int r = 0; r < 4; ++r) O[(size_t)(m + r) * 1024 + n] = acc[mi][ni][r] + bv;
      }
    }
  } else {
    unsigned short* O = (unsigned short*)out;
#pragma unroll
    for (int mi = 0; mi < 4; ++mi) {
      int m = mBase + mi * 16;
      int b = m >> 11, t = m & 2047;
#pragma unroll
      for (int ni = 0; ni < 4; ++ni) {
        int n = nBase + ni * 16;
        int h = n >> 6, d = n & 63;
        float bv = bias[n];
        if (MODE == 2) {
          ushort4 pk;
          pk.x = f2bf(acc[mi][ni][0] + bv);
          pk.y = f2bf(acc[mi][ni][1] + bv);
          pk.z = f2bf(acc[mi][ni][2] + bv);
          pk.w = f2bf(acc[mi][ni][3] + bv);
          *(ushort4*)&O[((size_t)((b * 16 + h) * 64 + d)) * 2048 + t] = pk;
        } else {
          const float sc = (MODE == 0) ? 0.125f : 1.0f;
#pragma unroll
          for (int r = 0; r < 4; ++r)
            O[((size_t)(b * 16 + h) * 2048 + (t + r)) * 64 + d] = f2bf((acc[mi][ni][r] + bv) * sc);
        }
      }
    }
  }
}

// ---------------------------------------------------------------- attention
// Swapped-QK^T in-register softmax; NO LDS; K/V frags direct from global (L2).
// Triangle pairing: block x -> bh = x&63, j = x>>6; wave w handles q-chunks
// (j*128 + w*32) and ((15-j)*128 + (3-w)*32): exactly 33 tiles per wave.
__global__ void __launch_bounds__(256) attn_kernel(const unsigned short* __restrict__ Q,
                                                   const unsigned short* __restrict__ K,
                                                   const unsigned short* __restrict__ Vt,
                                                   unsigned short* __restrict__ Y) {
  const int tid = threadIdx.x;
  const int wid = tid >> 6;
  const int l = tid & 63;
  const int q32 = l & 31;
  const int hi = l >> 5;
  const int bh = blockIdx.x & 63;
  const int j = blockIdx.x >> 6;  // 0..7

  const unsigned short* Qp = Q + (size_t)bh * 2048 * 64;
  const unsigned short* Kp = K + (size_t)bh * 2048 * 64;
  const unsigned short* Vp = Vt + (size_t)bh * 64 * 2048;
  const int b = bh >> 4, h = bh & 15;

  for (int cc = 0; cc < 2; ++cc) {
    const int q0w = (cc == 0) ? (j * 128 + wid * 32) : ((15 - j) * 128 + (3 - wid) * 32);
    const int myNt = (q0w + 95) >> 6;

    bf16x8 qf[4];
#pragma unroll
    for (int kk = 0; kk < 4; ++kk)
      qf[kk] = *(const bf16x8*)&Qp[(size_t)(q0w + q32) * 64 + kk * 16 + hi * 8];

    f32x16 o0, o1;
#pragma unroll
    for (int r = 0; r < 16; ++r) { o0[r] = 0.f; o1[r] = 0.f; }
    float m = -1e30f, lst = 0.f;

    for (int t = 0; t < myNt; ++t) {
      const int k0 = t * 64;

      // ---- K frags direct from global (L2-resident)
      bf16x8 kf0[4], kf1[4];
#pragma unroll
      for (int kk = 0; kk < 4; ++kk) {
        kf0[kk] = *(const bf16x8*)&Kp[(size_t)(k0 + q32) * 64 + kk * 16 + hi * 8];
        kf1[kk] = *(const bf16x8*)&Kp[(size_t)(k0 + 32 + q32) * 64 + kk * 16 + hi * 8];
      }

      // ---- QK^T (swapped): lane q32 holds full S^T column for its q
      f32x16 s0, s1;
#pragma unroll
      for (int r = 0; r < 16; ++r) { s0[r] = 0.f; s1[r] = 0.f; }
      __builtin_amdgcn_s_setprio(1);
#pragma unroll
      for (int kk = 0; kk < 4; ++kk) {
        s0 = MFMA32(kf0[kk], qf[kk], s0);
        s1 = MFMA32(kf1[kk], qf[kk], s1);
      }
      __builtin_amdgcn_s_setprio(0);

      // ---- V frags (issue early; softmax hides latency)
      bf16x8 vb0[4], vb1[4];
#pragma unroll
      for (int ks = 0; ks < 4; ++ks) {
        vb0[ks] = *(const bf16x8*)&Vp[(size_t)q32 * 2048 + k0 + ks * 16 + hi * 8];
        vb1[ks] = *(const bf16x8*)&Vp[(size_t)(32 + q32) * 2048 + k0 + ks * 16 + hi * 8];
      }

      // ---- causal mask (diagonal tile only)
      if (k0 + 63 > q0w) {
        const int qg = q0w + q32;
#pragma unroll
        for (int r = 0; r < 16; ++r) {
          int kr = (r & 3) + 8 * (r >> 2) + 4 * hi;
          if (k0 + kr > qg) s0[r] = -1e30f;
          if (k0 + 32 + kr > qg) s1[r] = -1e30f;
        }
      }

      // ---- online softmax (3-ary max groups -> v_max3)
      float pm = fmaxf(fmaxf(s0[0], s0[1]), s0[2]);
#pragma unroll
      for (int r = 3; r < 15; r += 3) pm = fmaxf(fmaxf(fmaxf(s0[r], s0[r + 1]), s0[r + 2]), pm);
      pm = fmaxf(pm, s0[15]);
#pragma unroll
      for (int r = 0; r < 15; r += 3) pm = fmaxf(fmaxf(fmaxf(s1[r], s1[r + 1]), s1[r + 2]), pm);
      pm = fmaxf(pm, s1[15]);
      pm = fmaxf(pm, __shfl_xor(pm, 32));

      if (__any(pm > m + 8.0f)) {
        float mn = fmaxf(m, pm);
        float sf = __expf(m - mn);
        m = mn;
        lst *= sf;
#pragma unroll
        for (int r = 0; r < 16; ++r) {
          float sb = __shfl(sf, (r & 3) + 8 * (r >> 2) + 4 * hi);
          o0[r] *= sb;
          o1[r] *= sb;
        }
      }
      float rs = 0.f;
#pragma unroll
      for (int r = 0; r < 16; ++r) { s0[r] = __expf(s0[r] - m); rs += s0[r]; }
#pragma unroll
      for (int r = 0; r < 16; ++r) { s1[r] = __expf(s1[r] - m); rs += s1[r]; }
      rs += __shfl_xor(rs, 32);
      lst += rs;

      // ---- P -> bf16 A-frags: 16 cvt_pk + 8 permlane32_swap
      union { unsigned int u[4]; bf16x8 v; } pa[4];
#pragma unroll
      for (int t2 = 0; t2 < 2; ++t2) {
        const f32x16& sv = t2 ? s1 : s0;
#pragma unroll
        for (int sl = 0; sl < 2; ++sl) {
          int base = sl * 8;
          unsigned int x0 = cvtpk(sv[base + 0], sv[base + 1]);
          unsigned int x1 = cvtpk(sv[base + 2], sv[base + 3]);
          unsigned int x2 = cvtpk(sv[base + 4], sv[base + 5]);
          unsigned int x3 = cvtpk(sv[base + 6], sv[base + 7]);
          plswap(x0, x2);
          plswap(x1, x3);
          int ksg = t2 * 2 + sl;
          pa[ksg].u[0] = x0; pa[ksg].u[1] = x1; pa[ksg].u[2] = x2; pa[ksg].u[3] = x3;
        }
      }

      // ---- PV
      __builtin_amdgcn_s_setprio(1);
#pragma unroll
      for (int ksg = 0; ksg < 4; ++ksg) {
        o0 = MFMA32(pa[ksg].v, vb0[ksg], o0);
        o1 = MFMA32(pa[ksg].v, vb1[ksg], o1);
      }
      __builtin_amdgcn_s_setprio(0);
    }

    // ---- epilogue
#pragma unroll
    for (int r = 0; r < 16; ++r) {
      int qsrc = (r & 3) + 8 * (r >> 2) + 4 * hi;
      int qg = q0w + qsrc;
      float lq = __shfl(lst, qsrc);
      float inv = 1.0f / lq;
      size_t rowb = (size_t)(b * 2048 + qg) * 1024 + h * 64;
      Y[rowb + q32] = f2bf(o0[r] * inv);
      Y[rowb + 32 + q32] = f2bf(o1[r] * inv);
    }
  }
}

// ---------------------------------------------------------------- launch
extern "C" void kernel_launch(void* const* d_in, const int* in_sizes, int n_in,
                              void* d_out, int out_size, void* d_ws, size_t ws_size,
                              hipStream_t stream) {
  const float* x = (const float*)d_in[0];
  const float* Wk = (const float*)d_in[1];
  const float* bk = (const float*)d_in[2];
  const float* Wq = (const float*)d_in[3];
  const float* bq = (const float*)d_in[4];
  const float* Wv = (const float*)d_in[5];
  const float* bv = (const float*)d_in[6];
  const float* Wp = (const float*)d_in[7];
  const float* bp = (const float*)d_in[8];
  float* out = (float*)d_out;

  char* ws = (char*)d_ws;
  unsigned short* xb  = (unsigned short*)(ws);
  unsigned short* wkb = (unsigned short*)(ws + 16777216);
  unsigned short* wqb = (unsigned short*)(ws + 18874368);
  unsigned short* wvb = (unsigned short*)(ws + 20971520);
  unsigned short* wpb = (unsigned short*)(ws + 23068672);
  unsigned short* Qb  = (unsigned short*)(ws + 25165824);
  unsigned short* Kb  = (unsigned short*)(ws + 41943040);
  unsigned short* Vtb = (unsigned short*)(ws + 58720256);
  unsigned short* yb  = (unsigned short*)(ws + 75497472);
  if (ws_size < 92274688u) return;

  cvt_f32_bf16<<<dim3(2048), dim3(256), 0, stream>>>(x, xb, 8388608 / 4);
  cvt_f32_bf16<<<dim3(1024), dim3(256), 0, stream>>>(Wk, wkb, 1048576 / 4);
  cvt_f32_bf16<<<dim3(1024), dim3(256), 0, stream>>>(Wq, wqb, 1048576 / 4);
  cvt_f32_bf16<<<dim3(1024), dim3(256), 0, stream>>>(Wv, wvb, 1048576 / 4);
  cvt_f32_bf16<<<dim3(1024), dim3(256), 0, stream>>>(Wp, wpb, 1048576 / 4);

  dim3 gg(8, 64);
  gemm_bt<1><<<gg, dim3(256), 0, stream>>>(xb, wkb, bk, (void*)Kb);
  gemm_bt<0><<<gg, dim3(256), 0, stream>>>(xb, wqb, bq, (void*)Qb);
  gemm_bt<2><<<gg, dim3(256), 0, stream>>>(xb, wvb, bv, (void*)Vtb);

  attn_kernel<<<dim3(512), dim3(256), 0, stream>>>(Qb, Kb, Vtb, yb);

  gemm_bt<3><<<gg, dim3(256), 0, stream>>>(yb, wpb, bp, (void*)out);
}

// Round 4
// 195.533 us; speedup vs baseline: 1.3357x; 1.3357x over previous
//
#include <hip/hip_runtime.h>
#include <stdint.h>

typedef short bf16x8 __attribute__((ext_vector_type(8)));
typedef float f32x4 __attribute__((ext_vector_type(4)));
typedef float f32x16 __attribute__((ext_vector_type(16)));

#define MFMA16(a, b, c) __builtin_amdgcn_mfma_f32_16x16x32_bf16((a), (b), (c), 0, 0, 0)
#define MFMA32(a, b, c) __builtin_amdgcn_mfma_f32_32x32x16_bf16((a), (b), (c), 0, 0, 0)

__device__ __forceinline__ unsigned short f2bf(float x) {
  union { float f; unsigned int u; } v; v.f = x;
  unsigned int r = (v.u + 0x7FFFu + ((v.u >> 16) & 1u)) >> 16;
  return (unsigned short)r;
}

__device__ __forceinline__ unsigned int cvtpk(float lo, float hi) {
  unsigned int r;
  asm("v_cvt_pk_bf16_f32 %0, %1, %2" : "=v"(r) : "v"(lo), "v"(hi));
  return r;
}

__device__ __forceinline__ void plswap(unsigned int& a, unsigned int& b) {
  asm("v_permlane32_swap_b32 %0, %1" : "+v"(a), "+v"(b));
}

__device__ __forceinline__ float exp2f_fast(float x) {
  float r;
  asm("v_exp_f32 %0, %1" : "=v"(r) : "v"(x));
  return r;
}

// ---------------------------------------------------------------- convert
__global__ void __launch_bounds__(256) cvt_f32_bf16(const float* __restrict__ in,
                                                    unsigned short* __restrict__ out,
                                                    int n4) {
  int i = blockIdx.x * blockDim.x + threadIdx.x;
  int stride = gridDim.x * blockDim.x;
  for (; i < n4; i += stride) {
    float4 v = ((const float4*)in)[i];
    ushort4 o;
    o.x = f2bf(v.x); o.y = f2bf(v.y); o.z = f2bf(v.z); o.w = f2bf(v.w);
    ((ushort4*)out)[i] = o;
  }
}

// ---------------------------------------------------------------- GEMM (unchanged)
template <int MODE>
__global__ void __launch_bounds__(256) gemm_bt(const unsigned short* __restrict__ A,
                                               const unsigned short* __restrict__ Bw,
                                               const float* __restrict__ bias,
                                               void* __restrict__ out) {
  constexpr int K = 1024;
  __shared__ unsigned short As[128 * 32];
  __shared__ unsigned short Bs[128 * 32];

  const int tid = threadIdx.x;
  const int wid = tid >> 6;
  const int l = tid & 63;
  const int g = l >> 4;
  const int ln = l & 15;

  const int m0 = blockIdx.y * 128;
  const int n0 = blockIdx.x * 128;
  const int wm = (wid >> 1) * 64;
  const int wn = (wid & 1) * 64;

  f32x4 acc[4][4];
  for (int i = 0; i < 4; ++i)
    for (int j = 0; j < 4; ++j) acc[i][j] = (f32x4){0.f, 0.f, 0.f, 0.f};

  const int s0 = wid * 2;
  const int rowBase = s0 * 16 + (l >> 2);
  const int cb = (l & 3) * 8;

  for (int kt = 0; kt < K; kt += 32) {
    __syncthreads();
#pragma unroll
    for (int i = 0; i < 2; ++i) {
      int row = rowBase + i * 16;
      const unsigned short* ga = A + (size_t)(m0 + row) * K + kt + cb;
      const unsigned short* gb = Bw + (size_t)(n0 + row) * K + kt + cb;
      __builtin_amdgcn_global_load_lds((const __attribute__((address_space(1))) void*)ga,
                                       (__attribute__((address_space(3))) void*)&As[(s0 + i) * 512],
                                       16, 0, 0);
      __builtin_amdgcn_global_load_lds((const __attribute__((address_space(1))) void*)gb,
                                       (__attribute__((address_space(3))) void*)&Bs[(s0 + i) * 512],
                                       16, 0, 0);
    }
    __syncthreads();

    bf16x8 af[4], bfr[4];
#pragma unroll
    for (int mi = 0; mi < 4; ++mi) af[mi] = *(const bf16x8*)&As[(wm + mi * 16 + ln) * 32 + g * 8];
#pragma unroll
    for (int ni = 0; ni < 4; ++ni) bfr[ni] = *(const bf16x8*)&Bs[(wn + ni * 16 + ln) * 32 + g * 8];
#pragma unroll
    for (int mi = 0; mi < 4; ++mi)
#pragma unroll
      for (int ni = 0; ni < 4; ++ni) acc[mi][ni] = MFMA16(af[mi], bfr[ni], acc[mi][ni]);
  }

  const int mBase = m0 + wm + g * 4;
  const int nBase = n0 + wn + ln;

  if (MODE == 3) {
    float* O = (float*)out;
#pragma unroll
    for (int mi = 0; mi < 4; ++mi) {
      int m = mBase + mi * 16;
#pragma unroll
      for (int ni = 0; ni < 4; ++ni) {
        int n = nBase + ni * 16;
        float bv = bias[n];
#pragma unroll
        for (int r = 0; r < 4; ++r) O[(size_t)(m + r) * 1024 + n] = acc[mi][ni][r] + bv;
      }
    }
  } else {
    unsigned short* O = (unsigned short*)out;
#pragma unroll
    for (int mi = 0; mi < 4; ++mi) {
      int m = mBase + mi * 16;
      int b = m >> 11, t = m & 2047;
#pragma unroll
      for (int ni = 0; ni < 4; ++ni) {
        int n = nBase + ni * 16;
        int h = n >> 6, d = n & 63;
        float bv = bias[n];
        if (MODE == 2) {
          ushort4 pk;
          pk.x = f2bf(acc[mi][ni][0] + bv);
          pk.y = f2bf(acc[mi][ni][1] + bv);
          pk.z = f2bf(acc[mi][ni][2] + bv);
          pk.w = f2bf(acc[mi][ni][3] + bv);
          *(ushort4*)&O[((size_t)((b * 16 + h) * 64 + d)) * 2048 + t] = pk;
        } else {
          // MODE 0 (Q): fold 1/sqrt(D) * log2(e) so softmax exp runs in exp2 domain
          const float sc = (MODE == 0) ? 0.125f * 1.44269504f : 1.0f;
#pragma unroll
          for (int r = 0; r < 4; ++r)
            O[((size_t)(b * 16 + h) * 2048 + (t + r)) * 64 + d] = f2bf((acc[mi][ni][r] + bv) * sc);
        }
      }
    }
  }
}

// ---------------------------------------------------------------- attention
// 8 waves x 32 q-rows = 256 contiguous q per block. KV tile 64, dbuf LDS.
// Block x: bh = x&63, hb = x>>6, sb = hb<4 ? 7-hb : hb-4.
// CU slot pairing (x, x+256) -> (sb, 7-sb): uniform 36 tile-units/CU, same bh.
__global__ void __launch_bounds__(512) attn_kernel(const unsigned short* __restrict__ Q,
                                                   const unsigned short* __restrict__ K,
                                                   const unsigned short* __restrict__ Vt,
                                                   unsigned short* __restrict__ Y) {
  __shared__ unsigned short Ks[2][64 * 64];
  __shared__ unsigned short Vs[2][64 * 64];

  const int tid = threadIdx.x;
  const int wid = tid >> 6;          // 0..7
  const int l = tid & 63;
  const int q32 = l & 31;
  const int hi = l >> 5;
  const int bh = blockIdx.x & 63;
  const int hb = blockIdx.x >> 6;
  const int sb = (hb < 4) ? (7 - hb) : (hb - 4);
  const int q0w = sb * 256 + wid * 32;
  const int NT = 4 * sb + 4;
  const int myNt = (q0w + 95) >> 6;  // ceil((q0w+32)/64)

  const unsigned short* Qp = Q + (size_t)bh * 2048 * 64;
  const unsigned short* Kp = K + (size_t)bh * 2048 * 64;
  const unsigned short* Vp = Vt + (size_t)bh * 64 * 2048;
  const int b = bh >> 4, h = bh & 15;

  // staging: thread covers one 16B chunk; row = wid*8 + (l>>3), chunk sc^(row&7)
  const int srow = wid * 8 + (l >> 3);
  const int csw = (l & 7) ^ (srow & 7);

  bf16x8 qf[4];
#pragma unroll
  for (int kk = 0; kk < 4; ++kk)
    qf[kk] = *(const bf16x8*)&Qp[(size_t)(q0w + q32) * 64 + kk * 16 + hi * 8];

  f32x16 o0, o1;
#pragma unroll
  for (int r = 0; r < 16; ++r) { o0[r] = 0.f; o1[r] = 0.f; }
  float m = -1e30f, lst = 0.f;

#define STAGE(bufi, kk0)                                                                        \
  {                                                                                             \
    const unsigned short* gk = Kp + (size_t)((kk0) + srow) * 64 + csw * 8;                      \
    const unsigned short* gv = Vp + (size_t)srow * 2048 + (kk0) + csw * 8;                      \
    __builtin_amdgcn_global_load_lds((const __attribute__((address_space(1))) void*)gk,         \
                                     (__attribute__((address_space(3))) void*)                  \
                                         &Ks[bufi][wid * 512],                                  \
                                     16, 0, 0);                                                 \
    __builtin_amdgcn_global_load_lds((const __attribute__((address_space(1))) void*)gv,         \
                                     (__attribute__((address_space(3))) void*)                  \
                                         &Vs[bufi][wid * 512],                                  \
                                     16, 0, 0);                                                 \
  }

  int buf = 0;
  STAGE(0, 0);
  __syncthreads();

  for (int t = 0; t < NT; ++t) {
    const int k0 = t * 64;
    if (t + 1 < NT) STAGE(buf ^ 1, k0 + 64);

    if (t < myNt) {
      const int xr = q32 & 7;
      // ---- QK^T (swapped): lane q32 holds S^T column for its q; S in log2 units
      f32x16 s0, s1;
#pragma unroll
      for (int r = 0; r < 16; ++r) { s0[r] = 0.f; s1[r] = 0.f; }
      __builtin_amdgcn_s_setprio(1);
#pragma unroll
      for (int kk = 0; kk < 4; ++kk) {
        bf16x8 kf0 = *(const bf16x8*)&Ks[buf][q32 * 64 + (((kk << 1) | hi) ^ xr) * 8];
        bf16x8 kf1 = *(const bf16x8*)&Ks[buf][(32 + q32) * 64 + (((kk << 1) | hi) ^ xr) * 8];
        s0 = MFMA32(kf0, qf[kk], s0);
        s1 = MFMA32(kf1, qf[kk], s1);
      }
      __builtin_amdgcn_s_setprio(0);

      // ---- causal mask (diagonal tiles only)
      if (k0 + 63 > q0w) {
        const int qg = q0w + q32;
#pragma unroll
        for (int r = 0; r < 16; ++r) {
          int kr = (r & 3) + 8 * (r >> 2) + 4 * hi;
          if (k0 + kr > qg) s0[r] = -1e30f;
          if (k0 + 32 + kr > qg) s1[r] = -1e30f;
        }
      }

      // ---- online softmax in exp2 domain, defer-max THR=11
      float pm = fmaxf(fmaxf(s0[0], s0[1]), s0[2]);
#pragma unroll
      for (int r = 3; r < 15; r += 3) pm = fmaxf(fmaxf(fmaxf(s0[r], s0[r + 1]), s0[r + 2]), pm);
      pm = fmaxf(pm, s0[15]);
#pragma unroll
      for (int r = 0; r < 15; r += 3) pm = fmaxf(fmaxf(fmaxf(s1[r], s1[r + 1]), s1[r + 2]), pm);
      pm = fmaxf(pm, s1[15]);
      pm = fmaxf(pm, __shfl_xor(pm, 32));

      if (__any(pm > m + 11.0f)) {
        float mn = fmaxf(m, pm);
        float sf = exp2f_fast(m - mn);
        m = mn;
        lst *= sf;
#pragma unroll
        for (int r = 0; r < 16; ++r) {
          float sb2 = __shfl(sf, (r & 3) + 8 * (r >> 2) + 4 * hi);
          o0[r] *= sb2;
          o1[r] *= sb2;
        }
      }
      float rs = 0.f;
#pragma unroll
      for (int r = 0; r < 16; ++r) { s0[r] = exp2f_fast(s0[r] - m); rs += s0[r]; }
#pragma unroll
      for (int r = 0; r < 16; ++r) { s1[r] = exp2f_fast(s1[r] - m); rs += s1[r]; }
      rs += __shfl_xor(rs, 32);
      lst += rs;

      // ---- P -> bf16 A-frags: 16 cvt_pk + 8 permlane32_swap
      union { unsigned int u[4]; bf16x8 v; } pa[4];
#pragma unroll
      for (int t2 = 0; t2 < 2; ++t2) {
        const f32x16& sv = t2 ? s1 : s0;
#pragma unroll
        for (int sl = 0; sl < 2; ++sl) {
          int base = sl * 8;
          unsigned int x0 = cvtpk(sv[base + 0], sv[base + 1]);
          unsigned int x1 = cvtpk(sv[base + 2], sv[base + 3]);
          unsigned int x2 = cvtpk(sv[base + 4], sv[base + 5]);
          unsigned int x3 = cvtpk(sv[base + 6], sv[base + 7]);
          plswap(x0, x2);
          plswap(x1, x3);
          int ksg = t2 * 2 + sl;
          pa[ksg].u[0] = x0; pa[ksg].u[1] = x1; pa[ksg].u[2] = x2; pa[ksg].u[3] = x3;
        }
      }

      // ---- PV
      __builtin_amdgcn_s_setprio(1);
#pragma unroll
      for (int ksg = 0; ksg < 4; ++ksg) {
        bf16x8 v0 = *(const bf16x8*)&Vs[buf][q32 * 64 + (((ksg << 1) | hi) ^ xr) * 8];
        bf16x8 v1 = *(const bf16x8*)&Vs[buf][(32 + q32) * 64 + (((ksg << 1) | hi) ^ xr) * 8];
        o0 = MFMA32(pa[ksg].v, v0, o0);
        o1 = MFMA32(pa[ksg].v, v1, o1);
      }
      __builtin_amdgcn_s_setprio(0);
    }

    __syncthreads();
    buf ^= 1;
  }

  // ---- epilogue
#pragma unroll
  for (int r = 0; r < 16; ++r) {
    int qsrc = (r & 3) + 8 * (r >> 2) + 4 * hi;
    int qg = q0w + qsrc;
    float lq = __shfl(lst, qsrc);
    float inv = 1.0f / lq;
    size_t rowb = (size_t)(b * 2048 + qg) * 1024 + h * 64;
    Y[rowb + q32] = f2bf(o0[r] * inv);
    Y[rowb + 32 + q32] = f2bf(o1[r] * inv);
  }
#undef STAGE
}

// ---------------------------------------------------------------- launch
extern "C" void kernel_launch(void* const* d_in, const int* in_sizes, int n_in,
                              void* d_out, int out_size, void* d_ws, size_t ws_size,
                              hipStream_t stream) {
  const float* x = (const float*)d_in[0];
  const float* Wk = (const float*)d_in[1];
  const float* bk = (const float*)d_in[2];
  const float* Wq = (const float*)d_in[3];
  const float* bq = (const float*)d_in[4];
  const float* Wv = (const float*)d_in[5];
  const float* bv = (const float*)d_in[6];
  const float* Wp = (const float*)d_in[7];
  const float* bp = (const float*)d_in[8];
  float* out = (float*)d_out;

  char* ws = (char*)d_ws;
  unsigned short* xb  = (unsigned short*)(ws);
  unsigned short* wkb = (unsigned short*)(ws + 16777216);
  unsigned short* wqb = (unsigned short*)(ws + 18874368);
  unsigned short* wvb = (unsigned short*)(ws + 20971520);
  unsigned short* wpb = (unsigned short*)(ws + 23068672);
  unsigned short* Qb  = (unsigned short*)(ws + 25165824);
  unsigned short* Kb  = (unsigned short*)(ws + 41943040);
  unsigned short* Vtb = (unsigned short*)(ws + 58720256);
  unsigned short* yb  = (unsigned short*)(ws + 75497472);
  if (ws_size < 92274688u) return;

  cvt_f32_bf16<<<dim3(2048), dim3(256), 0, stream>>>(x, xb, 8388608 / 4);
  cvt_f32_bf16<<<dim3(1024), dim3(256), 0, stream>>>(Wk, wkb, 1048576 / 4);
  cvt_f32_bf16<<<dim3(1024), dim3(256), 0, stream>>>(Wq, wqb, 1048576 / 4);
  cvt_f32_bf16<<<dim3(1024), dim3(256), 0, stream>>>(Wv, wvb, 1048576 / 4);
  cvt_f32_bf16<<<dim3(1024), dim3(256), 0, stream>>>(Wp, wpb, 1048576 / 4);

  dim3 gg(8, 64);
  gemm_bt<1><<<gg, dim3(256), 0, stream>>>(xb, wkb, bk, (void*)Kb);
  gemm_bt<0><<<gg, dim3(256), 0, stream>>>(xb, wqb, bq, (void*)Qb);
  gemm_bt<2><<<gg, dim3(256), 0, stream>>>(xb, wvb, bv, (void*)Vtb);

  attn_kernel<<<dim3(512), dim3(512), 0, stream>>>(Qb, Kb, Vtb, yb);

  gemm_bt<3><<<gg, dim3(256), 0, stream>>>(yb, wpb, bp, (void*)out);
}